// Round 8
// baseline (171.473 us; speedup 1.0000x reference)
//
#include <hip/hip_runtime.h>

#define BLOCK 256

// Branch-free BCE matching jnp: -(t*clip(log p,-100) + (1-t)*clip(log1p(-p),-100))
// log1p(-p) -> __logf(1-p): abs err ~6e-8, far inside the 2e3 threshold.
__device__ __forceinline__ float bce_elem(float p, float t) {
    float lp  = fmaxf(__logf(p), -100.0f);        // v_log_f32(0) = -inf -> clamped
    float l1p = fmaxf(__logf(1.0f - p), -100.0f);
    return -__builtin_fmaf(t, lp - l1p, l1p);     // -(t*(lp-l1p) + l1p)
}

// first index i in [0,n) with a[i] >= v  (a sorted ascending)
__device__ __forceinline__ int lower_bound(const int* __restrict__ a, int n, int v) {
    int lo = 0, hi = n;
    while (lo < hi) {
        int mid = (int)(((unsigned)lo + (unsigned)hi) >> 1);
        if (a[mid] < v) lo = mid + 1; else hi = mid;
    }
    return lo;
}

// One block per segment (B=2048 -> 8 blocks/CU). Hot loop: pure coalesced
// float4 stride loop over pred/tgt/mask (batch never streamed). Fused
// finalize: one atomicAdd per block into the scalar output.
__global__ __launch_bounds__(BLOCK) void seg_kernel(
    const float* __restrict__ pred, const float* __restrict__ tgt,
    const int* __restrict__ batch, const int* __restrict__ mask,
    const float* __restrict__ sat_pred, const float* __restrict__ sat_tgt,
    float* __restrict__ out, int n, int Bseg)
{
    const int b   = blockIdx.x;
    const int tid = threadIdx.x;

    __shared__ int sh_lo, sh_hi;
    if (tid == 0) sh_lo = lower_bound(batch, n, b);
    if (tid == 1) sh_hi = lower_bound(batch, n, b + 1);
    __syncthreads();
    const int lo = sh_lo, hi = sh_hi;          // this block owns batch range [lo,hi)

    float accb = 0.0f, accc = 0.0f;

    int a0 = (lo + 3) & ~3;                    // first 16B-aligned element
    if (a0 > hi) a0 = hi;
    const int nvec = (hi - a0) >> 2;
    const int a1   = a0 + (nvec << 2);

    // scalar head (<=3 elems)
    for (int i = lo + tid; i < a0; i += BLOCK) {
        float mf = (float)mask[i];
        accb += bce_elem(pred[i] * mf, tgt[i]);
        accc += mf;
    }
    // vector body: 3 coalesced float4 streams (plain loads -- nt measured worse)
    const float4* p4 = reinterpret_cast<const float4*>(pred) + (a0 >> 2);
    const float4* t4 = reinterpret_cast<const float4*>(tgt)  + (a0 >> 2);
    const int4*   m4 = reinterpret_cast<const int4*>(mask)   + (a0 >> 2);
    for (int i = tid; i < nvec; i += BLOCK) {
        float4 p = p4[i];
        float4 t = t4[i];
        int4   m = m4[i];
        float m0 = (float)m.x, m1 = (float)m.y, m2 = (float)m.z, m3 = (float)m.w;
        accb += bce_elem(p.x * m0, t.x);  accc += m0;
        accb += bce_elem(p.y * m1, t.y);  accc += m1;
        accb += bce_elem(p.z * m2, t.z);  accc += m2;
        accb += bce_elem(p.w * m3, t.w);  accc += m3;
    }
    // scalar tail (<=3 elems)
    for (int i = a1 + tid; i < hi; i += BLOCK) {
        float mf = (float)mask[i];
        accb += bce_elem(pred[i] * mf, tgt[i]);
        accc += mf;
    }

    // block reduction: wave shfl -> LDS -> thread 0
    #pragma unroll
    for (int o = 32; o > 0; o >>= 1) {
        accb += __shfl_xor(accb, o);
        accc += __shfl_xor(accc, o);
    }
    __shared__ float wb[4], wc[4];
    if ((tid & 63) == 0) { wb[tid >> 6] = accb; wc[tid >> 6] = accc; }
    __syncthreads();
    if (tid == 0) {
        float sb = wb[0] + wb[1] + wb[2] + wb[3];
        float sc = wc[0] + wc[1] + wc[2] + wc[3];
        float pg = (sc > 0.0f) ? sb / fmaxf(sc, 1.0f) : 0.0f;
        // fold this graph's share of the sat-BCE mean*L1 term
        pg += bce_elem(sat_pred[b], sat_tgt[b]) * ((1.0f / 50.0f) / (float)Bseg);
        atomicAdd(out, pg);                    // device-scope fp32 atomic, one line
    }
}

extern "C" void kernel_launch(void* const* d_in, const int* in_sizes, int n_in,
                              void* d_out, int out_size, void* d_ws, size_t ws_size,
                              hipStream_t stream) {
    const float* y_mus_pred = (const float*)d_in[0];
    const float* y_mus      = (const float*)d_in[1];
    const float* y_sat_pred = (const float*)d_in[2];
    const float* y_sat      = (const float*)d_in[3];
    const int*   batch      = (const int*)d_in[4];
    const int*   mask       = (const int*)d_in[5];

    const int n    = in_sizes[0];
    const int Bseg = in_sizes[2];

    // d_out is re-poisoned (0xAA) before every launch -> zero the scalar.
    hipMemsetAsync(d_out, 0, sizeof(float), stream);

    seg_kernel<<<Bseg, BLOCK, 0, stream>>>(
        y_mus_pred, y_mus, batch, mask, y_sat_pred, y_sat,
        (float*)d_out, n, Bseg);
}

// Round 9
// 156.463 us; speedup vs baseline: 1.0959x; 1.0959x over previous
//
#include <hip/hip_runtime.h>

#define BLOCK 256

// Branch-free BCE matching jnp: -(t*clip(log p,-100) + (1-t)*clip(log1p(-p),-100))
// log1p(-p) -> __logf(1-p): abs err ~6e-8, far inside the 2e3 threshold.
__device__ __forceinline__ float bce_elem(float p, float t) {
    float lp  = fmaxf(__logf(p), -100.0f);        // v_log_f32(0) = -inf -> clamped
    float l1p = fmaxf(__logf(1.0f - p), -100.0f);
    return -__builtin_fmaf(t, lp - l1p, l1p);     // -(t*(lp-l1p) + l1p)
}

// first index i in [0,n) with a[i] >= v  (a sorted ascending)
__device__ __forceinline__ int lower_bound(const int* __restrict__ a, int n, int v) {
    int lo = 0, hi = n;
    while (lo < hi) {
        int mid = (int)(((unsigned)lo + (unsigned)hi) >> 1);
        if (a[mid] < v) lo = mid + 1; else hi = mid;
    }
    return lo;
}

// One block per segment (B=2048 -> 8 blocks/CU). Hot loop: pure coalesced
// float4 stride loop over pred/tgt/mask (batch never streamed). Per-graph
// result stored non-atomically; separate 1-block sum kernel (measured
// cheaper than same-line device-scope atomics: 43 vs 57.5 us).
__global__ __launch_bounds__(BLOCK) void seg_kernel(
    const float* __restrict__ pred, const float* __restrict__ tgt,
    const int* __restrict__ batch, const int* __restrict__ mask,
    const float* __restrict__ sat_pred, const float* __restrict__ sat_tgt,
    float* __restrict__ per_graph, int n, int Bseg)
{
    const int b   = blockIdx.x;
    const int tid = threadIdx.x;

    __shared__ int sh_lo, sh_hi;
    if (tid == 0) sh_lo = lower_bound(batch, n, b);
    if (tid == 1) sh_hi = lower_bound(batch, n, b + 1);
    __syncthreads();
    const int lo = sh_lo, hi = sh_hi;          // this block owns batch range [lo,hi)

    float accb = 0.0f, accc = 0.0f;

    int a0 = (lo + 3) & ~3;                    // first 16B-aligned element
    if (a0 > hi) a0 = hi;
    const int nvec = (hi - a0) >> 2;
    const int a1   = a0 + (nvec << 2);

    // scalar head (<=3 elems)
    for (int i = lo + tid; i < a0; i += BLOCK) {
        float mf = (float)mask[i];
        accb += bce_elem(pred[i] * mf, tgt[i]);
        accc += mf;
    }
    // vector body: 3 coalesced float4 streams (plain loads -- nt measured worse)
    const float4* p4 = reinterpret_cast<const float4*>(pred) + (a0 >> 2);
    const float4* t4 = reinterpret_cast<const float4*>(tgt)  + (a0 >> 2);
    const int4*   m4 = reinterpret_cast<const int4*>(mask)   + (a0 >> 2);
    for (int i = tid; i < nvec; i += BLOCK) {
        float4 p = p4[i];
        float4 t = t4[i];
        int4   m = m4[i];
        float m0 = (float)m.x, m1 = (float)m.y, m2 = (float)m.z, m3 = (float)m.w;
        accb += bce_elem(p.x * m0, t.x);  accc += m0;
        accb += bce_elem(p.y * m1, t.y);  accc += m1;
        accb += bce_elem(p.z * m2, t.z);  accc += m2;
        accb += bce_elem(p.w * m3, t.w);  accc += m3;
    }
    // scalar tail (<=3 elems)
    for (int i = a1 + tid; i < hi; i += BLOCK) {
        float mf = (float)mask[i];
        accb += bce_elem(pred[i] * mf, tgt[i]);
        accc += mf;
    }

    // block reduction: wave shfl -> LDS -> thread 0
    #pragma unroll
    for (int o = 32; o > 0; o >>= 1) {
        accb += __shfl_xor(accb, o);
        accc += __shfl_xor(accc, o);
    }
    __shared__ float wb[4], wc[4];
    if ((tid & 63) == 0) { wb[tid >> 6] = accb; wc[tid >> 6] = accc; }
    __syncthreads();
    if (tid == 0) {
        float sb = wb[0] + wb[1] + wb[2] + wb[3];
        float sc = wc[0] + wc[1] + wc[2] + wc[3];
        float pg = (sc > 0.0f) ? sb / fmaxf(sc, 1.0f) : 0.0f;
        // fold this graph's share of the sat-BCE mean*L1 term; every b covered once
        pg += bce_elem(sat_pred[b], sat_tgt[b]) * ((1.0f / 50.0f) / (float)Bseg);
        per_graph[b] = pg;                      // plain store: no atomics anywhere
    }
}

__global__ __launch_bounds__(256) void sum_kernel(
    const float* __restrict__ per_graph, float* __restrict__ out, int Bseg)
{
    float local = 0.0f;
    for (int i = threadIdx.x; i < Bseg; i += 256) local += per_graph[i];
    #pragma unroll
    for (int o = 32; o > 0; o >>= 1) local += __shfl_xor(local, o);
    __shared__ float ws[4];
    if ((threadIdx.x & 63) == 0) ws[threadIdx.x >> 6] = local;
    __syncthreads();
    if (threadIdx.x == 0) out[0] = ws[0] + ws[1] + ws[2] + ws[3];
}

extern "C" void kernel_launch(void* const* d_in, const int* in_sizes, int n_in,
                              void* d_out, int out_size, void* d_ws, size_t ws_size,
                              hipStream_t stream) {
    const float* y_mus_pred = (const float*)d_in[0];
    const float* y_mus      = (const float*)d_in[1];
    const float* y_sat_pred = (const float*)d_in[2];
    const float* y_sat      = (const float*)d_in[3];
    const int*   batch      = (const int*)d_in[4];
    const int*   mask       = (const int*)d_in[5];

    const int n    = in_sizes[0];
    const int Bseg = in_sizes[2];

    float* per_graph = (float*)d_ws;   // Bseg floats; every slot written each launch

    seg_kernel<<<Bseg, BLOCK, 0, stream>>>(
        y_mus_pred, y_mus, batch, mask, y_sat_pred, y_sat, per_graph, n, Bseg);
    sum_kernel<<<1, 256, 0, stream>>>(per_graph, (float*)d_out, Bseg);
}